// Round 7
// baseline (848.504 us; speedup 1.0000x reference)
//
#include <hip/hip_runtime.h>

typedef unsigned short u16;
typedef unsigned int   u32;
typedef __bf16  bf16x8 __attribute__((ext_vector_type(8)));
typedef float   f32x4  __attribute__((ext_vector_type(4)));
typedef unsigned int u32x4 __attribute__((ext_vector_type(4)));
typedef unsigned int u32x2 __attribute__((ext_vector_type(2)));

__device__ __forceinline__ float bf2f(u16 h){ return __uint_as_float(((u32)h)<<16); }
__device__ __forceinline__ u16 f2bf(float f){
  u32 u = __float_as_uint(f);
  u += 0x7FFFu + ((u>>16)&1u);
  return (u16)(u>>16);
}
__device__ __forceinline__ f32x4 mfma16(bf16x8 a, bf16x8 b, f32x4 c){
  return __builtin_amdgcn_mfma_f32_16x16x32_bf16(a,b,c,0,0,0);
}

// ---------------- fp32 -> bf16 convert (4 elems/thread) ----------------
__global__ __launch_bounds__(256) void cvt_kernel(const float* __restrict__ in,
                                                  u16* __restrict__ out, int n4){
  int i = blockIdx.x*256 + threadIdx.x;
  if (i < n4){
    float4 v = ((const float4*)in)[i];
    u32 p0 = (u32)f2bf(v.x) | ((u32)f2bf(v.y)<<16);
    u32 p1 = (u32)f2bf(v.z) | ((u32)f2bf(v.w)<<16);
    u32x2 pv = {p0, p1};
    *(u32x2*)(out + (size_t)i*4) = pv;
  }
}

// ---------------- dt = softplus(u @ W_A^T) in fp32 (full 16384 tokens) ----------------
__global__ __launch_bounds__(256) void dt_kernel(const float* __restrict__ u,
                                                 const float* __restrict__ Win,
                                                 float* __restrict__ dtb){
  __shared__ float us[8][1028];
  const int tid = threadIdx.x;
  const size_t t0 = (size_t)blockIdx.x*8;
  for (int i=tid; i<2048; i+=256){
    int row = i>>8, col = (i&255)*4;
    *(float4*)&us[row][col] = *(const float4*)(u + (t0+row)*1024 + col);
  }
  __syncthreads();
  const int tok = tid & 7, h = tid >> 3;
  const float* wp = Win + (size_t)(6144+h)*1024;
  float s0=0.f,s1=0.f,s2=0.f,s3=0.f;
  for (int k=0;k<1024;k+=4){
    float4 a  = *(const float4*)&us[tok][k];
    float4 wv = *(const float4*)&wp[k];
    s0 += a.x*wv.x; s1 += a.y*wv.y; s2 += a.z*wv.z; s3 += a.w*wv.w;
  }
  float s = (s0+s1)+(s2+s3);
  dtb[(t0+tok)*32 + h] = (s > 15.f) ? s : log1pf(expf(s));
}

// ---------------- in_proj GEMM: A fp32 (on-the-fly bf16), B bf16, NT ----------------
// cols<5120 -> xbc_raw bf16 ; 5120..6143 -> gate=silu(z+zb) bf16
__global__ __launch_bounds__(256,2) void gemm_in(const float* __restrict__ A,
                                                 const u16* __restrict__ Bw,
                                                 u16* __restrict__ out0,
                                                 u16* __restrict__ out1,
                                                 const float* __restrict__ zb){
  __shared__ u16 As[128*40];
  __shared__ u16 Bs[128*40];
  const int tid  = threadIdx.x;
  const int lane = tid & 63;
  const int w = tid >> 6, wm = w >> 1, wn = w & 1;
  const int quad = lane >> 4, l15 = lane & 15;
  const size_t m0 = (size_t)blockIdx.y*128, n0 = (size_t)blockIdx.x*128;

  f32x4 acc[4][4];
  #pragma unroll
  for (int i=0;i<4;i++)
    #pragma unroll
    for (int j=0;j<4;j++){ f32x4 z = {0.f,0.f,0.f,0.f}; acc[i][j] = z; }

  const int srow = tid >> 2;
  const int scol = (tid & 3) * 8;

  for (int k0 = 0; k0 < 1024; k0 += 32){
    __syncthreads();
    #pragma unroll
    for (int p=0;p<2;p++){
      int row = srow + p*64;
      const float* ap = A + (m0+row)*1024 + k0 + scol;
      float4 a0 = *(const float4*)ap;
      float4 a1 = *(const float4*)(ap+4);
      u32 w0 = (u32)f2bf(a0.x) | ((u32)f2bf(a0.y)<<16);
      u32 w1 = (u32)f2bf(a0.z) | ((u32)f2bf(a0.w)<<16);
      u32 w2 = (u32)f2bf(a1.x) | ((u32)f2bf(a1.y)<<16);
      u32 w3 = (u32)f2bf(a1.z) | ((u32)f2bf(a1.w)<<16);
      u32x4 va = {w0,w1,w2,w3};
      *(u32x4*)&As[row*40 + scol] = va;
      u32x4 vb = *(const u32x4*)(Bw + (n0+row)*1024 + k0 + scol);
      *(u32x4*)&Bs[row*40 + scol] = vb;
    }
    __syncthreads();
    bf16x8 av[4], bv[4];
    #pragma unroll
    for (int mi=0;mi<4;mi++) av[mi] = *(const bf16x8*)&As[(wm*64+mi*16+l15)*40 + quad*8];
    #pragma unroll
    for (int ni=0;ni<4;ni++) bv[ni] = *(const bf16x8*)&Bs[(wn*64+ni*16+l15)*40 + quad*8];
    #pragma unroll
    for (int mi=0;mi<4;mi++)
      #pragma unroll
      for (int ni=0;ni<4;ni++)
        acc[mi][ni] = mfma16(av[mi], bv[ni], acc[mi][ni]);
  }

  #pragma unroll
  for (int mi=0;mi<4;mi++){
    #pragma unroll
    for (int ni=0;ni<4;ni++){
      #pragma unroll
      for (int r=0;r<4;r++){
        size_t row = m0 + wm*64 + mi*16 + quad*4 + r;
        int    col = (int)n0 + wn*64 + ni*16 + l15;
        float v = acc[mi][ni][r];
        if (col < 5120){
          out0[row*5120 + col] = f2bf(v);
        } else {
          int ch = col - 5120;
          float z = v + zb[ch];
          float sg = z / (1.f + __expf(-z));
          out1[row*1024 + ch] = f2bf(sg);
        }
      }
    }
  }
}

// ---------------- out GEMM (bf16 MFMA, FP32 STORE to d_out) ----------------
__global__ __launch_bounds__(256,2) void gemm_out(const u16* __restrict__ A,
                                                  const u16* __restrict__ Bw,
                                                  float* __restrict__ out0){
  __shared__ u16 As[128*40];
  __shared__ u16 Bs[128*40];
  const int tid  = threadIdx.x;
  const int lane = tid & 63;
  const int w = tid >> 6, wm = w >> 1, wn = w & 1;
  const int quad = lane >> 4, l15 = lane & 15;
  const size_t m0 = (size_t)blockIdx.y*128, n0 = (size_t)blockIdx.x*128;

  f32x4 acc[4][4];
  #pragma unroll
  for (int i=0;i<4;i++)
    #pragma unroll
    for (int j=0;j<4;j++){ f32x4 z = {0.f,0.f,0.f,0.f}; acc[i][j] = z; }

  const int srow = tid >> 2;
  const int scol = (tid & 3) * 8;

  for (int k0 = 0; k0 < 1024; k0 += 32){
    __syncthreads();
    #pragma unroll
    for (int p=0;p<2;p++){
      int row = srow + p*64;
      u32x4 va = *(const u32x4*)(A  + (m0+row)*1024 + k0 + scol);
      u32x4 vb = *(const u32x4*)(Bw + (n0+row)*1024 + k0 + scol);
      *(u32x4*)&As[row*40 + scol] = va;
      *(u32x4*)&Bs[row*40 + scol] = vb;
    }
    __syncthreads();
    bf16x8 av[4], bv[4];
    #pragma unroll
    for (int mi=0;mi<4;mi++) av[mi] = *(const bf16x8*)&As[(wm*64+mi*16+l15)*40 + quad*8];
    #pragma unroll
    for (int ni=0;ni<4;ni++) bv[ni] = *(const bf16x8*)&Bs[(wn*64+ni*16+l15)*40 + quad*8];
    #pragma unroll
    for (int mi=0;mi<4;mi++)
      #pragma unroll
      for (int ni=0;ni<4;ni++)
        acc[mi][ni] = mfma16(av[mi], bv[ni], acc[mi][ni]);
  }

  #pragma unroll
  for (int mi=0;mi<4;mi++)
    #pragma unroll
    for (int ni=0;ni<4;ni++)
      #pragma unroll
      for (int r=0;r<4;r++){
        size_t row = m0 + wm*64 + mi*16 + quad*4 + r;
        int    col = (int)n0 + wn*64 + ni*16 + l15;
        out0[row*1024 + col] = acc[mi][ni][r];   // fp32 store
      }
}

// ---------------- causal depthwise conv1d (DCONV=4), per-batch ----------------
__global__ __launch_bounds__(256) void conv_kernel(const u16* __restrict__ xraw,
                                                   const float* __restrict__ cw,
                                                   const float* __restrict__ cb,
                                                   u16* __restrict__ xconv){
  const int c  = blockIdx.x*256 + threadIdx.x;
  const int t0 = blockIdx.y*8;
  const float w0=cw[c*4+0], w1=cw[c*4+1], w2=cw[c*4+2], w3=cw[c*4+3], bias=cb[c];
  const size_t base = (size_t)c;
  float h0 = (t0>=3) ? bf2f(xraw[base + (size_t)(t0-3)*5120]) : 0.f;
  float h1 = (t0>=2) ? bf2f(xraw[base + (size_t)(t0-2)*5120]) : 0.f;
  float h2 = (t0>=1) ? bf2f(xraw[base + (size_t)(t0-1)*5120]) : 0.f;
  #pragma unroll
  for (int i=0;i<8;i++){
    float x = bf2f(xraw[base + (size_t)(t0+i)*5120]);
    float o = w0*h0 + w1*h1 + w2*h2 + w3*x + bias;
    xconv[base + (size_t)(t0+i)*5120] = f2bf(o);
    h0=h1; h1=h2; h2=x;
  }
}

// ---------------- chunk kernel 1 (per-batch): Y_diag + D*x, states, dc ----------------
__global__ __launch_bounds__(256,1) void chunk1_kernel(const u16* __restrict__ xconv,
                                                       const float* __restrict__ dtb,
                                                       const float* __restrict__ Dvec,
                                                       float* __restrict__ ypart,
                                                       float* __restrict__ states,
                                                       float* __restrict__ dcb){
  __shared__ u16 Ps[128*136];
  __shared__ u16 XT[32*136];
  __shared__ u16 BT[64*136];
  __shared__ float Acum[128];
  __shared__ float decay[128];

  const int tid = threadIdx.x;
  const int lane = tid & 63;
  const int w = tid >> 6, quad = lane >> 4, l15 = lane & 15;
  const int blk = blockIdx.x;               // c*32 + h
  const int h = blk & 31, c = blk >> 5;
  const size_t tok0 = (size_t)c*128;
  const size_t xbase = tok0 * 5120;

  float mdt = 0.f;
  if (tid < 128) mdt = -dtb[(tok0 + tid)*32 + h];

  #pragma unroll
  for (int p=0;p<2;p++){
    int idx = p*256 + tid;
    int row = idx >> 2, col = (idx & 3)*8;
    u32x4 v = *(const u32x4*)(xconv + xbase + (size_t)row*5120 + h*32 + col);
    const u16* pv = (const u16*)&v;
    #pragma unroll
    for (int j=0;j<8;j++) XT[(col+j)*136 + row] = pv[j];
  }
  #pragma unroll
  for (int p=0;p<4;p++){
    int idx = p*256 + tid;
    int row = idx >> 3, col = (idx & 7)*8;
    u32x4 v = *(const u32x4*)(xconv + xbase + (size_t)row*5120 + 1024 + h*64 + col);
    const u16* pv = (const u16*)&v;
    #pragma unroll
    for (int j=0;j<8;j++) BT[(col+j)*136 + row] = pv[j];
  }
  if (tid < 128) Acum[tid] = mdt;
  __syncthreads();
  float run = mdt;
  for (int off=1; off<128; off<<=1){
    float add = 0.f;
    if (tid < 128 && tid >= off) add = Acum[tid-off];
    __syncthreads();
    if (tid < 128){ run += add; Acum[tid] = run; }
    __syncthreads();
  }
  float Alast = Acum[127];
  if (tid < 128) decay[tid] = __expf(Alast - Acum[tid]);
  if (tid == 0)  dcb[blk] = __expf(Alast);

  const int wm = w >> 1, wn = w & 1;
  f32x4 g[4][4];
  #pragma unroll
  for (int i=0;i<4;i++)
    #pragma unroll
    for (int j=0;j<4;j++){ f32x4 z = {0.f,0.f,0.f,0.f}; g[i][j] = z; }
  #pragma unroll
  for (int kk=0; kk<2; kk++){
    bf16x8 av[4], bv[4];
    #pragma unroll
    for (int mi=0;mi<4;mi++){
      int row = wm*64 + mi*16 + l15;
      av[mi] = *(const bf16x8*)(xconv + xbase + (size_t)row*5120 + 3072 + h*64 + kk*32 + quad*8);
    }
    #pragma unroll
    for (int ni=0;ni<4;ni++){
      int row = wn*64 + ni*16 + l15;
      bv[ni] = *(const bf16x8*)(xconv + xbase + (size_t)row*5120 + 1024 + h*64 + kk*32 + quad*8);
    }
    #pragma unroll
    for (int mi=0;mi<4;mi++)
      #pragma unroll
      for (int ni=0;ni<4;ni++)
        g[mi][ni] = mfma16(av[mi], bv[ni], g[mi][ni]);
  }
  #pragma unroll
  for (int mi=0;mi<4;mi++){
    int rowb = wm*64 + mi*16 + quad*4;
    #pragma unroll
    for (int ni=0;ni<4;ni++){
      int col = wn*64 + ni*16 + l15;
      float ac = Acum[col];
      #pragma unroll
      for (int r=0;r<4;r++){
        int row = rowb + r;
        float val = 0.f;
        if (col <= row) val = g[mi][ni][r] * __expf(Acum[row] - ac);
        Ps[row*136 + col] = f2bf(val);
      }
    }
  }
  __syncthreads();

  f32x4 yd[2][2];
  #pragma unroll
  for (int i=0;i<2;i++)
    #pragma unroll
    for (int j=0;j<2;j++){ f32x4 z = {0.f,0.f,0.f,0.f}; yd[i][j] = z; }
  #pragma unroll
  for (int kk=0;kk<4;kk++){
    bf16x8 av[2], bv[2];
    #pragma unroll
    for (int mi=0;mi<2;mi++) av[mi] = *(const bf16x8*)&Ps[(w*32+mi*16+l15)*136 + kk*32 + quad*8];
    #pragma unroll
    for (int ni=0;ni<2;ni++) bv[ni] = *(const bf16x8*)&XT[(ni*16+l15)*136 + kk*32 + quad*8];
    #pragma unroll
    for (int mi=0;mi<2;mi++)
      #pragma unroll
      for (int ni=0;ni<2;ni++)
        yd[mi][ni] = mfma16(av[mi], bv[ni], yd[mi][ni]);
  }
  float Dh = Dvec[h];
  #pragma unroll
  for (int mi=0;mi<2;mi++)
    #pragma unroll
    for (int ni=0;ni<2;ni++)
      #pragma unroll
      for (int r=0;r<4;r++){
        int row = w*32 + mi*16 + quad*4 + r;
        int col = ni*16 + l15;
        float xval = bf2f(XT[col*136 + row]);
        ypart[(tok0+row)*1024 + h*32 + col] = yd[mi][ni][r] + Dh*xval;
      }

  const int wm2 = w >> 1, wn2 = w & 1;
  f32x4 st[2];
  { f32x4 z = {0.f,0.f,0.f,0.f}; st[0]=z; st[1]=z; }
  #pragma unroll
  for (int kk=0;kk<4;kk++){
    bf16x8 av;
    {
      u32x4 xv = *(const u32x4*)&XT[(wm2*16+l15)*136 + kk*32 + quad*8];
      const u16* xp = (const u16*)&xv;
      #pragma unroll
      for (int j=0;j<8;j++) ((__bf16*)&av)[j] = (__bf16)(bf2f(xp[j]) * decay[kk*32 + quad*8 + j]);
    }
    bf16x8 bv[2];
    #pragma unroll
    for (int ni=0;ni<2;ni++) bv[ni] = *(const bf16x8*)&BT[(wn2*32+ni*16+l15)*136 + kk*32 + quad*8];
    #pragma unroll
    for (int ni=0;ni<2;ni++) st[ni] = mfma16(av, bv[ni], st[ni]);
  }
  size_t sbase = (size_t)blk * 2048;
  #pragma unroll
  for (int ni=0;ni<2;ni++)
    #pragma unroll
    for (int r=0;r<4;r++){
      int row = wm2*16 + quad*4 + r;
      int col = wn2*32 + ni*16 + l15;
      states[sbase + row*64 + col] = st[ni][r];
    }
}

// ---------------- inter-chunk scan (per-batch, in-place states -> prevs) ----------------
__global__ __launch_bounds__(256) void scan_kernel(float* __restrict__ states,
                                                   const float* __restrict__ dcb){
  const int h = blockIdx.x >> 3;
  const int part = blockIdx.x & 7;
  const int pn = part*256 + threadIdx.x;
  float S = 0.f;
  for (int c=0;c<64;c++){
    size_t idx = ((size_t)(c*32 + h))*2048 + pn;
    float stv = states[idx];
    float d = dcb[c*32 + h];
    states[idx] = S;
    S = S*d + stv;
  }
}

// ---------------- chunk kernel 3 (per-batch): Y_off + gate ----------------
__global__ __launch_bounds__(256,1) void chunk3_kernel(const u16* __restrict__ xconv,
                                                       const float* __restrict__ dtb,
                                                       const float* __restrict__ prevs,
                                                       const float* __restrict__ ypart,
                                                       const u16* __restrict__ gate,
                                                       u16* __restrict__ yg){
  __shared__ u16 Pv[32*72];
  __shared__ float Acum[128];
  const int tid = threadIdx.x;
  const int lane = tid & 63;
  const int w = tid >> 6, quad = lane >> 4, l15 = lane & 15;
  const int blk = blockIdx.x;
  const int h = blk & 31, c = blk >> 5;
  const size_t tok0 = (size_t)c*128;
  const size_t xbase = tok0 * 5120;

  float mdt = 0.f;
  if (tid < 128) mdt = -dtb[(tok0 + tid)*32 + h];
  size_t sbase = (size_t)blk * 2048;
  #pragma unroll
  for (int p=0;p<8;p++){
    int i = p*256 + tid;
    int pp = i >> 6, nn = i & 63;
    Pv[pp*72 + nn] = f2bf(prevs[sbase + i]);
  }
  if (tid < 128) Acum[tid] = mdt;
  __syncthreads();
  float run = mdt;
  for (int off=1; off<128; off<<=1){
    float add = 0.f;
    if (tid < 128 && tid >= off) add = Acum[tid-off];
    __syncthreads();
    if (tid < 128){ run += add; Acum[tid] = run; }
    __syncthreads();
  }

  f32x4 yo[2][2];
  #pragma unroll
  for (int i=0;i<2;i++)
    #pragma unroll
    for (int j=0;j<2;j++){ f32x4 z = {0.f,0.f,0.f,0.f}; yo[i][j] = z; }
  #pragma unroll
  for (int kk=0;kk<2;kk++){
    bf16x8 av[2], bv[2];
    #pragma unroll
    for (int mi=0;mi<2;mi++){
      int row = w*32 + mi*16 + l15;
      av[mi] = *(const bf16x8*)(xconv + xbase + (size_t)row*5120 + 3072 + h*64 + kk*32 + quad*8);
    }
    #pragma unroll
    for (int ni=0;ni<2;ni++) bv[ni] = *(const bf16x8*)&Pv[(ni*16+l15)*72 + kk*32 + quad*8];
    #pragma unroll
    for (int mi=0;mi<2;mi++)
      #pragma unroll
      for (int ni=0;ni<2;ni++)
        yo[mi][ni] = mfma16(av[mi], bv[ni], yo[mi][ni]);
  }
  #pragma unroll
  for (int mi=0;mi<2;mi++)
    #pragma unroll
    for (int ni=0;ni<2;ni++)
      #pragma unroll
      for (int r=0;r<4;r++){
        int row = w*32 + mi*16 + quad*4 + r;
        int col = ni*16 + l15;
        size_t gi = (tok0+row)*1024 + h*32 + col;
        float val = (ypart[gi] + __expf(Acum[row]) * yo[mi][ni][r]) * bf2f(gate[gi]);
        yg[gi] = f2bf(val);
      }
}

// ---------------- host ----------------
extern "C" void kernel_launch(void* const* d_in, const int* in_sizes, int n_in,
                              void* d_out, int out_size, void* d_ws, size_t ws_size,
                              hipStream_t stream){
  (void)out_size; (void)ws_size;
  // Inputs identified by element count (all distinct); positional fallback.
  static const int want[7] = {16777216, 6324224, 20480, 5120, 1024, 32, 1048576};
  const void* src[7] = {nullptr,nullptr,nullptr,nullptr,nullptr,nullptr,nullptr};
  if (n_in >= 7){
    for (int i=0;i<7;i++)
      for (int j=0;j<n_in;j++)
        if (in_sizes[j] == want[i]){ src[i] = d_in[j]; break; }
  }
  bool ok = true;
  for (int i=0;i<7;i++) if (!src[i]) ok = false;
  if (!ok) for (int i=0;i<7;i++) src[i] = d_in[i];
  const float* u      = (const float*)src[0];
  const float* W_in   = (const float*)src[1];
  const float* conv_w = (const float*)src[2];
  const float* conv_b = (const float*)src[3];
  const float* z_bias = (const float*)src[4];
  const float* Dvec   = (const float*)src[5];
  const float* W_out  = (const float*)src[6];
  float* out = (float*)d_out;                             // OUTPUT IS FP32

  char* p = (char*)d_ws;
  u16* wi_bf   = (u16*)p;   p += (size_t)6144*1024*2;     // 12 MiB
  u16* wo_bf   = (u16*)p;   p += (size_t)1024*1024*2;     // 2 MiB
  float* dtb   = (float*)p; p += (size_t)16384*32*4;      // 2 MiB
  u16* yg      = (u16*)p;   p += (size_t)16384*1024*2;    // 32 MiB
  float* dcb   = (float*)p; p += (size_t)4096*4;          // 16 KiB
  u16* gate    = (u16*)p;   p += (size_t)8192*1024*2;     // 16 MiB
  char* xbcA   = p;         p += (size_t)8192*5120*2;     // 80 MiB
  u16* xconv   = (u16*)p;   p += (size_t)8192*5120*2;     // 80 MiB

  u16*   xbc_raw = (u16*)xbcA;
  float* ypart   = (float*)xbcA;                          // alias (xbc_raw dead after conv)
  float* states  = (float*)(xbcA + (size_t)8192*1024*4);  // alias, +32 MiB

  cvt_kernel<<<6144, 256, 0, stream>>>(W_in,  wi_bf, 6144*1024/4);
  cvt_kernel<<<1024, 256, 0, stream>>>(W_out, wo_bf, 1024*1024/4);
  dt_kernel<<<2048, 256, 0, stream>>>(u, W_in, dtb);

  for (int b = 0; b < 2; b++){
    const float* u_b   = u   + (size_t)b*8192*1024;
    float*       dtb_b = dtb + (size_t)b*8192*32;
    float*       dcb_b = dcb + (size_t)b*2048;
    u16*         yg_b  = yg  + (size_t)b*8192*1024;
    gemm_in<<<dim3(48,64), 256, 0, stream>>>(u_b, wi_bf, xbc_raw, gate, z_bias);
    conv_kernel<<<dim3(20,1024), 256, 0, stream>>>(xbc_raw, conv_w, conv_b, xconv);
    chunk1_kernel<<<2048, 256, 0, stream>>>(xconv, dtb_b, Dvec, ypart, states, dcb_b);
    scan_kernel<<<256, 256, 0, stream>>>(states, dcb_b);
    chunk3_kernel<<<2048, 256, 0, stream>>>(xconv, dtb_b, states, ypart, gate, yg_b);
  }
  gemm_out<<<dim3(8,128), 256, 0, stream>>>(yg, wo_bf, out);
}

// Round 8
// 791.746 us; speedup vs baseline: 1.0717x; 1.0717x over previous
//
#include <hip/hip_runtime.h>

typedef unsigned short u16;
typedef unsigned int   u32;
typedef __bf16  bf16x8 __attribute__((ext_vector_type(8)));
typedef float   f32x4  __attribute__((ext_vector_type(4)));
typedef unsigned int u32x4 __attribute__((ext_vector_type(4)));
typedef unsigned int u32x2 __attribute__((ext_vector_type(2)));

__device__ __forceinline__ float bf2f(u16 h){ return __uint_as_float(((u32)h)<<16); }
__device__ __forceinline__ u16 f2bf(float f){
  u32 u = __float_as_uint(f);
  u += 0x7FFFu + ((u>>16)&1u);
  return (u16)(u>>16);
}
__device__ __forceinline__ f32x4 mfma16(bf16x8 a, bf16x8 b, f32x4 c){
  return __builtin_amdgcn_mfma_f32_16x16x32_bf16(a,b,c,0,0,0);
}
// async global->LDS, 16B per lane (dest = wave-uniform base + lane*16)
__device__ __forceinline__ void ld16_lds(const u16* g, u16* l){
  __builtin_amdgcn_global_load_lds((const __attribute__((address_space(1))) u32*)g,
                                   (__attribute__((address_space(3))) u32*)l, 16, 0, 0);
}

// ---------------- fp32 -> bf16 convert (4 elems/thread) ----------------
__global__ __launch_bounds__(256) void cvt_kernel(const float* __restrict__ in,
                                                  u16* __restrict__ out, int n4){
  int i = blockIdx.x*256 + threadIdx.x;
  if (i < n4){
    float4 v = ((const float4*)in)[i];
    u32 p0 = (u32)f2bf(v.x) | ((u32)f2bf(v.y)<<16);
    u32 p1 = (u32)f2bf(v.z) | ((u32)f2bf(v.w)<<16);
    u32x2 pv = {p0, p1};
    *(u32x2*)(out + (size_t)i*4) = pv;
  }
}

// ---------------- dt = softplus(u @ W_A^T) in fp32 (full 16384 tokens) ----------------
__global__ __launch_bounds__(256) void dt_kernel(const float* __restrict__ u,
                                                 const float* __restrict__ Win,
                                                 float* __restrict__ dtb){
  __shared__ float us[8][1028];
  const int tid = threadIdx.x;
  const size_t t0 = (size_t)blockIdx.x*8;
  for (int i=tid; i<2048; i+=256){
    int row = i>>8, col = (i&255)*4;
    *(float4*)&us[row][col] = *(const float4*)(u + (t0+row)*1024 + col);
  }
  __syncthreads();
  const int tok = tid & 7, h = tid >> 3;
  const float* wp = Win + (size_t)(6144+h)*1024;
  float s0=0.f,s1=0.f,s2=0.f,s3=0.f;
  for (int k=0;k<1024;k+=4){
    float4 a  = *(const float4*)&us[tok][k];
    float4 wv = *(const float4*)&wp[k];
    s0 += a.x*wv.x; s1 += a.y*wv.y; s2 += a.z*wv.z; s3 += a.w*wv.w;
  }
  float s = (s0+s1)+(s2+s3);
  dtb[(t0+tok)*32 + h] = (s > 15.f) ? s : log1pf(expf(s));
}

// ---------------- in_proj GEMM (bf16 NT, async global->LDS staging) ----------------
// cols<5120 -> xbc_raw bf16 ; 5120..6143 -> gate=silu(z+zb) bf16
__global__ __launch_bounds__(256,2) void gemm_in(const u16* __restrict__ A,
                                                 const u16* __restrict__ Bw,
                                                 u16* __restrict__ out0,
                                                 u16* __restrict__ out1,
                                                 const float* __restrict__ zb){
  __shared__ u16 As[128*32];
  __shared__ u16 Bs[128*32];
  const int tid  = threadIdx.x;
  const int lane = tid & 63;
  const int w = tid >> 6, wm = w >> 1, wn = w & 1;
  const int quad = lane >> 4, l15 = lane & 15;
  const size_t m0 = (size_t)blockIdx.y*128, n0 = (size_t)blockIdx.x*128;

  f32x4 acc[4][4];
  #pragma unroll
  for (int i=0;i<4;i++)
    #pragma unroll
    for (int j=0;j<4;j++){ f32x4 z = {0.f,0.f,0.f,0.f}; acc[i][j] = z; }

  // staging: wave w covers rows [w*16, w*16+16) (chunk0) and +64 (chunk1)
  const int srow = w*16 + (lane>>2);
  const int scol = (lane&3)*8;
  const u16* gA = A  + (m0+srow)*1024 + scol;
  const u16* gB = Bw + (n0+srow)*1024 + scol;
  u16* lA = As + w*512;     // = w*16 rows * 32 u16
  u16* lB = Bs + w*512;

  for (int k0 = 0; k0 < 1024; k0 += 32){
    __syncthreads();                      // prev iter frag reads done
    ld16_lds(gA,          lA);
    ld16_lds(gA + 64*1024, lA + 2048);
    ld16_lds(gB,          lB);
    ld16_lds(gB + 64*1024, lB + 2048);
    gA += 32; gB += 32;
    __syncthreads();                      // drains vmcnt(0) before barrier
    bf16x8 av[4], bv[4];
    #pragma unroll
    for (int mi=0;mi<4;mi++) av[mi] = *(const bf16x8*)&As[(wm*64+mi*16+l15)*32 + quad*8];
    #pragma unroll
    for (int ni=0;ni<4;ni++) bv[ni] = *(const bf16x8*)&Bs[(wn*64+ni*16+l15)*32 + quad*8];
    #pragma unroll
    for (int mi=0;mi<4;mi++)
      #pragma unroll
      for (int ni=0;ni<4;ni++)
        acc[mi][ni] = mfma16(av[mi], bv[ni], acc[mi][ni]);
  }

  #pragma unroll
  for (int mi=0;mi<4;mi++){
    #pragma unroll
    for (int ni=0;ni<4;ni++){
      #pragma unroll
      for (int r=0;r<4;r++){
        size_t row = m0 + wm*64 + mi*16 + quad*4 + r;
        int    col = (int)n0 + wn*64 + ni*16 + l15;
        float v = acc[mi][ni][r];
        if (col < 5120){
          out0[row*5120 + col] = f2bf(v);
        } else {
          int ch = col - 5120;
          float z = v + zb[ch];
          float sg = z / (1.f + __expf(-z));
          out1[row*1024 + ch] = f2bf(sg);
        }
      }
    }
  }
}

// ---------------- out GEMM (bf16 NT, async staging, fp32 store) ----------------
__global__ __launch_bounds__(256,2) void gemm_out(const u16* __restrict__ A,
                                                  const u16* __restrict__ Bw,
                                                  float* __restrict__ out0){
  __shared__ u16 As[128*32];
  __shared__ u16 Bs[128*32];
  const int tid  = threadIdx.x;
  const int lane = tid & 63;
  const int w = tid >> 6, wm = w >> 1, wn = w & 1;
  const int quad = lane >> 4, l15 = lane & 15;
  const size_t m0 = (size_t)blockIdx.y*128, n0 = (size_t)blockIdx.x*128;

  f32x4 acc[4][4];
  #pragma unroll
  for (int i=0;i<4;i++)
    #pragma unroll
    for (int j=0;j<4;j++){ f32x4 z = {0.f,0.f,0.f,0.f}; acc[i][j] = z; }

  const int srow = w*16 + (lane>>2);
  const int scol = (lane&3)*8;
  const u16* gA = A  + (m0+srow)*1024 + scol;
  const u16* gB = Bw + (n0+srow)*1024 + scol;
  u16* lA = As + w*512;
  u16* lB = Bs + w*512;

  for (int k0 = 0; k0 < 1024; k0 += 32){
    __syncthreads();
    ld16_lds(gA,          lA);
    ld16_lds(gA + 64*1024, lA + 2048);
    ld16_lds(gB,          lB);
    ld16_lds(gB + 64*1024, lB + 2048);
    gA += 32; gB += 32;
    __syncthreads();
    bf16x8 av[4], bv[4];
    #pragma unroll
    for (int mi=0;mi<4;mi++) av[mi] = *(const bf16x8*)&As[(wm*64+mi*16+l15)*32 + quad*8];
    #pragma unroll
    for (int ni=0;ni<4;ni++) bv[ni] = *(const bf16x8*)&Bs[(wn*64+ni*16+l15)*32 + quad*8];
    #pragma unroll
    for (int mi=0;mi<4;mi++)
      #pragma unroll
      for (int ni=0;ni<4;ni++)
        acc[mi][ni] = mfma16(av[mi], bv[ni], acc[mi][ni]);
  }

  #pragma unroll
  for (int mi=0;mi<4;mi++)
    #pragma unroll
    for (int ni=0;ni<4;ni++)
      #pragma unroll
      for (int r=0;r<4;r++){
        size_t row = m0 + wm*64 + mi*16 + quad*4 + r;
        int    col = (int)n0 + wn*64 + ni*16 + l15;
        out0[row*1024 + col] = acc[mi][ni][r];
      }
}

// ---------------- causal depthwise conv1d (DCONV=4), per-batch ----------------
__global__ __launch_bounds__(256) void conv_kernel(const u16* __restrict__ xraw,
                                                   const float* __restrict__ cw,
                                                   const float* __restrict__ cb,
                                                   u16* __restrict__ xconv){
  const int c  = blockIdx.x*256 + threadIdx.x;
  const int t0 = blockIdx.y*8;
  const float w0=cw[c*4+0], w1=cw[c*4+1], w2=cw[c*4+2], w3=cw[c*4+3], bias=cb[c];
  const size_t base = (size_t)c;
  float h0 = (t0>=3) ? bf2f(xraw[base + (size_t)(t0-3)*5120]) : 0.f;
  float h1 = (t0>=2) ? bf2f(xraw[base + (size_t)(t0-2)*5120]) : 0.f;
  float h2 = (t0>=1) ? bf2f(xraw[base + (size_t)(t0-1)*5120]) : 0.f;
  #pragma unroll
  for (int i=0;i<8;i++){
    float x = bf2f(xraw[base + (size_t)(t0+i)*5120]);
    float o = w0*h0 + w1*h1 + w2*h2 + w3*x + bias;
    xconv[base + (size_t)(t0+i)*5120] = f2bf(o);
    h0=h1; h1=h2; h2=x;
  }
}

// ---------------- chunk kernel 1 (per-batch): Y_diag + D*x, states, dc ----------------
__global__ __launch_bounds__(256,1) void chunk1_kernel(const u16* __restrict__ xconv,
                                                       const float* __restrict__ dtb,
                                                       const float* __restrict__ Dvec,
                                                       float* __restrict__ ypart,
                                                       float* __restrict__ states,
                                                       float* __restrict__ dcb){
  __shared__ u16 Ps[128*136];
  __shared__ u16 XT[32*136];
  __shared__ u16 BT[64*136];
  __shared__ float Acum[128];
  __shared__ float decay[128];

  const int tid = threadIdx.x;
  const int lane = tid & 63;
  const int w = tid >> 6, quad = lane >> 4, l15 = lane & 15;
  const int blk = blockIdx.x;               // c*32 + h
  const int h = blk & 31, c = blk >> 5;
  const size_t tok0 = (size_t)c*128;
  const size_t xbase = tok0 * 5120;

  float mdt = 0.f;
  if (tid < 128) mdt = -dtb[(tok0 + tid)*32 + h];

  #pragma unroll
  for (int p=0;p<2;p++){
    int idx = p*256 + tid;
    int row = idx >> 2, col = (idx & 3)*8;
    u32x4 v = *(const u32x4*)(xconv + xbase + (size_t)row*5120 + h*32 + col);
    const u16* pv = (const u16*)&v;
    #pragma unroll
    for (int j=0;j<8;j++) XT[(col+j)*136 + row] = pv[j];
  }
  #pragma unroll
  for (int p=0;p<4;p++){
    int idx = p*256 + tid;
    int row = idx >> 3, col = (idx & 7)*8;
    u32x4 v = *(const u32x4*)(xconv + xbase + (size_t)row*5120 + 1024 + h*64 + col);
    const u16* pv = (const u16*)&v;
    #pragma unroll
    for (int j=0;j<8;j++) BT[(col+j)*136 + row] = pv[j];
  }
  if (tid < 128) Acum[tid] = mdt;
  __syncthreads();
  float run = mdt;
  for (int off=1; off<128; off<<=1){
    float add = 0.f;
    if (tid < 128 && tid >= off) add = Acum[tid-off];
    __syncthreads();
    if (tid < 128){ run += add; Acum[tid] = run; }
    __syncthreads();
  }
  float Alast = Acum[127];
  if (tid < 128) decay[tid] = __expf(Alast - Acum[tid]);
  if (tid == 0)  dcb[blk] = __expf(Alast);

  const int wm = w >> 1, wn = w & 1;
  f32x4 g[4][4];
  #pragma unroll
  for (int i=0;i<4;i++)
    #pragma unroll
    for (int j=0;j<4;j++){ f32x4 z = {0.f,0.f,0.f,0.f}; g[i][j] = z; }
  #pragma unroll
  for (int kk=0; kk<2; kk++){
    bf16x8 av[4], bv[4];
    #pragma unroll
    for (int mi=0;mi<4;mi++){
      int row = wm*64 + mi*16 + l15;
      av[mi] = *(const bf16x8*)(xconv + xbase + (size_t)row*5120 + 3072 + h*64 + kk*32 + quad*8);
    }
    #pragma unroll
    for (int ni=0;ni<4;ni++){
      int row = wn*64 + ni*16 + l15;
      bv[ni] = *(const bf16x8*)(xconv + xbase + (size_t)row*5120 + 1024 + h*64 + kk*32 + quad*8);
    }
    #pragma unroll
    for (int mi=0;mi<4;mi++)
      #pragma unroll
      for (int ni=0;ni<4;ni++)
        g[mi][ni] = mfma16(av[mi], bv[ni], g[mi][ni]);
  }
  #pragma unroll
  for (int mi=0;mi<4;mi++){
    int rowb = wm*64 + mi*16 + quad*4;
    #pragma unroll
    for (int ni=0;ni<4;ni++){
      int col = wn*64 + ni*16 + l15;
      float ac = Acum[col];
      #pragma unroll
      for (int r=0;r<4;r++){
        int row = rowb + r;
        float val = 0.f;
        if (col <= row) val = g[mi][ni][r] * __expf(Acum[row] - ac);
        Ps[row*136 + col] = f2bf(val);
      }
    }
  }
  __syncthreads();

  f32x4 yd[2][2];
  #pragma unroll
  for (int i=0;i<2;i++)
    #pragma unroll
    for (int j=0;j<2;j++){ f32x4 z = {0.f,0.f,0.f,0.f}; yd[i][j] = z; }
  #pragma unroll
  for (int kk=0;kk<4;kk++){
    bf16x8 av[2], bv[2];
    #pragma unroll
    for (int mi=0;mi<2;mi++) av[mi] = *(const bf16x8*)&Ps[(w*32+mi*16+l15)*136 + kk*32 + quad*8];
    #pragma unroll
    for (int ni=0;ni<2;ni++) bv[ni] = *(const bf16x8*)&XT[(ni*16+l15)*136 + kk*32 + quad*8];
    #pragma unroll
    for (int mi=0;mi<2;mi++)
      #pragma unroll
      for (int ni=0;ni<2;ni++)
        yd[mi][ni] = mfma16(av[mi], bv[ni], yd[mi][ni]);
  }
  float Dh = Dvec[h];
  #pragma unroll
  for (int mi=0;mi<2;mi++)
    #pragma unroll
    for (int ni=0;ni<2;ni++)
      #pragma unroll
      for (int r=0;r<4;r++){
        int row = w*32 + mi*16 + quad*4 + r;
        int col = ni*16 + l15;
        float xval = bf2f(XT[col*136 + row]);
        ypart[(tok0+row)*1024 + h*32 + col] = yd[mi][ni][r] + Dh*xval;
      }

  const int wm2 = w >> 1, wn2 = w & 1;
  f32x4 st[2];
  { f32x4 z = {0.f,0.f,0.f,0.f}; st[0]=z; st[1]=z; }
  #pragma unroll
  for (int kk=0;kk<4;kk++){
    bf16x8 av;
    {
      u32x4 xv = *(const u32x4*)&XT[(wm2*16+l15)*136 + kk*32 + quad*8];
      const u16* xp = (const u16*)&xv;
      #pragma unroll
      for (int j=0;j<8;j++) ((__bf16*)&av)[j] = (__bf16)(bf2f(xp[j]) * decay[kk*32 + quad*8 + j]);
    }
    bf16x8 bv[2];
    #pragma unroll
    for (int ni=0;ni<2;ni++) bv[ni] = *(const bf16x8*)&BT[(wn2*32+ni*16+l15)*136 + kk*32 + quad*8];
    #pragma unroll
    for (int ni=0;ni<2;ni++) st[ni] = mfma16(av, bv[ni], st[ni]);
  }
  size_t sbase = (size_t)blk * 2048;
  #pragma unroll
  for (int ni=0;ni<2;ni++)
    #pragma unroll
    for (int r=0;r<4;r++){
      int row = wm2*16 + quad*4 + r;
      int col = wn2*32 + ni*16 + l15;
      states[sbase + row*64 + col] = st[ni][r];
    }
}

// ---------------- inter-chunk scan (per-batch, in-place states -> prevs) ----------------
__global__ __launch_bounds__(256) void scan_kernel(float* __restrict__ states,
                                                   const float* __restrict__ dcb){
  const int h = blockIdx.x >> 3;
  const int part = blockIdx.x & 7;
  const int pn = part*256 + threadIdx.x;
  float S = 0.f;
  for (int c=0;c<64;c++){
    size_t idx = ((size_t)(c*32 + h))*2048 + pn;
    float stv = states[idx];
    float d = dcb[c*32 + h];
    states[idx] = S;
    S = S*d + stv;
  }
}

// ---------------- chunk kernel 3 (per-batch): Y_off + gate ----------------
__global__ __launch_bounds__(256,1) void chunk3_kernel(const u16* __restrict__ xconv,
                                                       const float* __restrict__ dtb,
                                                       const float* __restrict__ prevs,
                                                       const float* __restrict__ ypart,
                                                       const u16* __restrict__ gate,
                                                       u16* __restrict__ yg){
  __shared__ u16 Pv[32*72];
  __shared__ float Acum[128];
  const int tid = threadIdx.x;
  const int lane = tid & 63;
  const int w = tid >> 6, quad = lane >> 4, l15 = lane & 15;
  const int blk = blockIdx.x;
  const int h = blk & 31, c = blk >> 5;
  const size_t tok0 = (size_t)c*128;
  const size_t xbase = tok0 * 5120;

  float mdt = 0.f;
  if (tid < 128) mdt = -dtb[(tok0 + tid)*32 + h];
  size_t sbase = (size_t)blk * 2048;
  #pragma unroll
  for (int p=0;p<8;p++){
    int i = p*256 + tid;
    int pp = i >> 6, nn = i & 63;
    Pv[pp*72 + nn] = f2bf(prevs[sbase + i]);
  }
  if (tid < 128) Acum[tid] = mdt;
  __syncthreads();
  float run = mdt;
  for (int off=1; off<128; off<<=1){
    float add = 0.f;
    if (tid < 128 && tid >= off) add = Acum[tid-off];
    __syncthreads();
    if (tid < 128){ run += add; Acum[tid] = run; }
    __syncthreads();
  }

  f32x4 yo[2][2];
  #pragma unroll
  for (int i=0;i<2;i++)
    #pragma unroll
    for (int j=0;j<2;j++){ f32x4 z = {0.f,0.f,0.f,0.f}; yo[i][j] = z; }
  #pragma unroll
  for (int kk=0;kk<2;kk++){
    bf16x8 av[2], bv[2];
    #pragma unroll
    for (int mi=0;mi<2;mi++){
      int row = w*32 + mi*16 + l15;
      av[mi] = *(const bf16x8*)(xconv + xbase + (size_t)row*5120 + 3072 + h*64 + kk*32 + quad*8);
    }
    #pragma unroll
    for (int ni=0;ni<2;ni++) bv[ni] = *(const bf16x8*)&Pv[(ni*16+l15)*72 + kk*32 + quad*8];
    #pragma unroll
    for (int mi=0;mi<2;mi++)
      #pragma unroll
      for (int ni=0;ni<2;ni++)
        yo[mi][ni] = mfma16(av[mi], bv[ni], yo[mi][ni]);
  }
  #pragma unroll
  for (int mi=0;mi<2;mi++)
    #pragma unroll
    for (int ni=0;ni<2;ni++)
      #pragma unroll
      for (int r=0;r<4;r++){
        int row = w*32 + mi*16 + quad*4 + r;
        int col = ni*16 + l15;
        size_t gi = (tok0+row)*1024 + h*32 + col;
        float val = (ypart[gi] + __expf(Acum[row]) * yo[mi][ni][r]) * bf2f(gate[gi]);
        yg[gi] = f2bf(val);
      }
}

// ---------------- host ----------------
extern "C" void kernel_launch(void* const* d_in, const int* in_sizes, int n_in,
                              void* d_out, int out_size, void* d_ws, size_t ws_size,
                              hipStream_t stream){
  (void)out_size; (void)ws_size;
  static const int want[7] = {16777216, 6324224, 20480, 5120, 1024, 32, 1048576};
  const void* src[7] = {nullptr,nullptr,nullptr,nullptr,nullptr,nullptr,nullptr};
  if (n_in >= 7){
    for (int i=0;i<7;i++)
      for (int j=0;j<n_in;j++)
        if (in_sizes[j] == want[i]){ src[i] = d_in[j]; break; }
  }
  bool ok = true;
  for (int i=0;i<7;i++) if (!src[i]) ok = false;
  if (!ok) for (int i=0;i<7;i++) src[i] = d_in[i];
  const float* u      = (const float*)src[0];
  const float* W_in   = (const float*)src[1];
  const float* conv_w = (const float*)src[2];
  const float* conv_b = (const float*)src[3];
  const float* z_bias = (const float*)src[4];
  const float* Dvec   = (const float*)src[5];
  const float* W_out  = (const float*)src[6];
  float* out = (float*)d_out;                             // fp32 output

  // workspace: 240 MiB total
  char* p = (char*)d_ws;
  u16* wi_bf   = (u16*)p;   p += (size_t)6144*1024*2;     // 12 MiB
  u16* wo_bf   = (u16*)p;   p += (size_t)1024*1024*2;     // 2 MiB
  u16* u_bf    = (u16*)p;   p += (size_t)16384*1024*2;    // 32 MiB
  float* dtb   = (float*)p; p += (size_t)16384*32*4;      // 2 MiB
  float* dcb   = (float*)p; p += (size_t)4096*4;          // 16 KiB
  u16* gate    = (u16*)p;   p += (size_t)8192*1024*2;     // 16 MiB (per-batch)
  u16* yg      = (u16*)p;   p += (size_t)8192*1024*2;     // 16 MiB (per-batch)
  char* xbcA   = p;         p += (size_t)8192*5120*2;     // 80 MiB (per-batch)
  u16* xconv   = (u16*)p;   p += (size_t)8192*5120*2;     // 80 MiB (per-batch)

  u16*   xbc_raw = (u16*)xbcA;
  float* ypart   = (float*)xbcA;                          // alias (xbc_raw dead after conv)
  float* states  = (float*)(xbcA + (size_t)8192*1024*4);  // alias, +32 MiB

  cvt_kernel<<<16384, 256, 0, stream>>>(u,     u_bf,  16384*1024/4);
  cvt_kernel<<<6144,  256, 0, stream>>>(W_in,  wi_bf, 6144*1024/4);
  cvt_kernel<<<1024,  256, 0, stream>>>(W_out, wo_bf, 1024*1024/4);
  dt_kernel<<<2048, 256, 0, stream>>>(u, W_in, dtb);

  for (int b = 0; b < 2; b++){
    const u16* ub_bf = u_bf + (size_t)b*8192*1024;
    float*     dtb_b = dtb  + (size_t)b*8192*32;
    float*     dcb_b = dcb  + (size_t)b*2048;
    float*     out_b = out  + (size_t)b*8192*1024;
    gemm_in<<<dim3(48,64), 256, 0, stream>>>(ub_bf, wi_bf, xbc_raw, gate, z_bias);
    conv_kernel<<<dim3(20,1024), 256, 0, stream>>>(xbc_raw, conv_w, conv_b, xconv);
    chunk1_kernel<<<2048, 256, 0, stream>>>(xconv, dtb_b, Dvec, ypart, states, dcb_b);
    scan_kernel<<<256, 256, 0, stream>>>(states, dcb_b);
    chunk3_kernel<<<2048, 256, 0, stream>>>(xconv, dtb_b, states, ypart, gate, yg);
    gemm_out<<<dim3(8,64), 256, 0, stream>>>(yg, wo_bf, out_b);
  }
}